// Round 2
// baseline (3573.882 us; speedup 1.0000x reference)
//
#include <hip/hip_runtime.h>
#include <hip/hip_bf16.h>

// Grid LSTM (tanh grid-RNN), D=2, S=T=48, B=32, H=256. f32 in/out; bf16 MFMA
// internally. Persistent systolic columns, one block per (d, t) walking s.
// v3: inter-block handoff via bf16 staged images in a ws ring (depth 8):
//  - producer converts h_x (and layer0 h_y) to bf16 in MFMA A-frag layout and
//    bypass-stores 16KB per plane; drains; flags. f32 `out` stores are plain
//    cached (no peer consumes them) and happen AFTER the flag.
//  - consumer reads fragments DIRECT TO REGISTERS with agent-scope dword
//    atomic loads (LLC-coherent; ring slots are reused within a launch so
//    plain cached loads are illegal). No cvt, no LDS, no barrier on the hop.
//  - ring back-pressure uses the consumers' own production flags (cell s may
//    overwrite slot s&7 once consumers finished cell s-8). Provably acyclic.
//  - T = up@Ux + left@Uy computed ONCE per cell (64 MFMAs), added to both
//    accx/accy in the epilogue (was 128 MFMAs on the hot path).
//  - flagA (after hx-stage drain) gates the left neighbor; flagB (after
//    hy-stage drain) gates layer 1's x/y consumption.

typedef short short8 __attribute__((ext_vector_type(8)));
typedef float f32x4 __attribute__((ext_vector_type(4)));
typedef int   i32x4 __attribute__((ext_vector_type(4)));

static constexpr size_t UF_OFF    = 0;                           // 512 KiB U frags (bf16)
static constexpr size_t WF_OFF    = 512u * 1024;                 // 256 KiB W frags (bf16)
static constexpr size_t SRCW_OFF  = 768u * 1024;                 // 1.5 MiB f32 (acc layout)
static constexpr size_t TRGW_OFF  = SRCW_OFF + 48u * 32 * 256 * 4;
static constexpr size_t FLAG0_OFF = TRGW_OFF + 48u * 32 * 256 * 4;  // 48*48 lines x 128B
static constexpr size_t FLAG1_OFF = FLAG0_OFF + 48u * 48 * 128;
static constexpr size_t STG0X_OFF = FLAG1_OFF + 48u * 48 * 128;  // 48 t x 8 slots x 16KB
static constexpr size_t STG0Y_OFF = STG0X_OFF + 48u * 8 * 16384;
static constexpr size_t STG1X_OFF = STG0Y_OFF + 48u * 8 * 16384;
// total ws use ~= 23.3 MiB

#define MFMA16(a, b, c) __builtin_amdgcn_mfma_f32_16x16x32_bf16(a, b, c, 0, 0, 0)

__device__ __forceinline__ short f2bf(float f) {
  __hip_bfloat16 h = __float2bfloat16(f);
  return __builtin_bit_cast(short, h);
}

__device__ __forceinline__ size_t plane_off(int d, int s, int t, int c) {
  return (size_t)(((d * 48 + s) * 48 + t) * 2 + c) * 8192u;  // f32 elements
}

__device__ __forceinline__ int* flagp(char* ws, size_t off, int s, int t) {
  return (int*)(ws + off) + (size_t)(s * 48 + t) * 32;  // one 128B line per cell
}

__device__ __forceinline__ void wait_ge(int* p, int v) {
  while (__hip_atomic_load(p, __ATOMIC_RELAXED, __HIP_MEMORY_SCOPE_AGENT) < v)
    __builtin_amdgcn_s_sleep(1);
  asm volatile("" ::: "memory");  // keep subsequent loads below the spin
}

// bypass 2B store -> LLC (visible agent-wide once vmcnt retires)
__device__ __forceinline__ void st_llc_u16(unsigned short* p, unsigned short v) {
  __hip_atomic_store(p, v, __ATOMIC_RELAXED, __HIP_MEMORY_SCOPE_AGENT);
}

// 16B fragment load, LLC-coherent (agent scope), direct to registers.
__device__ __forceinline__ short8 ld_stg16(const char* p) {
  const int* ip = (const int*)p;
  i32x4 r;
  r.x = __hip_atomic_load(ip + 0, __ATOMIC_RELAXED, __HIP_MEMORY_SCOPE_AGENT);
  r.y = __hip_atomic_load(ip + 1, __ATOMIC_RELAXED, __HIP_MEMORY_SCOPE_AGENT);
  r.z = __hip_atomic_load(ip + 2, __ATOMIC_RELAXED, __HIP_MEMORY_SCOPE_AGENT);
  r.w = __hip_atomic_load(ip + 3, __ATOMIC_RELAXED, __HIP_MEMORY_SCOPE_AGENT);
  return __builtin_bit_cast(short8, r);
}

__device__ __forceinline__ float fast_tanh(float x) {
  float e = exp2f(x * 2.88539008f);
  return 1.f - __fdividef(2.f, e + 1.f);
}

// ---------------------------------------------------------------------------
// Kernel 1: U (2,512,256) f32 and W (2,256,256) f32 -> bf16 MFMA B-fragments.
// ---------------------------------------------------------------------------
__global__ void preswizzle(const float* __restrict__ U,
                           const float* __restrict__ W,
                           char* __restrict__ ws) {
  int gid = blockIdx.x * 256 + threadIdx.x;
  if (gid < 32768) {  // U
    int r = gid >> 11;
    int d = r >> 3, nh = (r >> 2) & 1, w = r & 3;
    int c = gid & 2047;
    int f = c >> 6, lane = c & 63;
    int nt = f >> 4, ks = f & 15;
    int kbase = ks * 32 + (lane >> 4) * 8;
    int n = nh * 128 + w * 32 + nt * 16 + (lane & 15);
    const float* sp = U + (size_t)d * 512 * 256 + n;
    short8 v;
#pragma unroll
    for (int j = 0; j < 8; ++j) v[j] = f2bf(sp[(size_t)(kbase + j) * 256]);
    *(short8*)(ws + UF_OFF + (size_t)gid * 16) = v;
  } else {            // W
    int idx = gid - 32768;
    int r = idx >> 10;
    int d = r >> 3, nh = (r >> 2) & 1, w = r & 3;
    int c = idx & 1023;
    int f = c >> 6, lane = c & 63;
    int nt = f >> 3, ks = f & 7;
    int kbase = ks * 32 + (lane >> 4) * 8;
    int n = nh * 128 + w * 32 + nt * 16 + (lane & 15);
    const float* sp = W + (size_t)d * 256 * 256 + n;
    short8 v;
#pragma unroll
    for (int j = 0; j < 8; ++j) v[j] = f2bf(sp[(size_t)(kbase + j) * 256]);
    *(short8*)(ws + WF_OFF + (size_t)idx * 16) = v;
  }
}

// ---------------------------------------------------------------------------
// Kernel 2: SRCW[s] = src[s]@W0 + b0 ; TRGW[t] = trg[t]@W0 + b0  (f32),
// stored in grid_main's per-thread accumulator layout: [i][gtid][16].
// ---------------------------------------------------------------------------
__global__ __launch_bounds__(256, 1) void precompute_xw(
    const float* __restrict__ src, const float* __restrict__ trg,
    const float* __restrict__ bvec, char* __restrict__ ws) {
  __shared__ __align__(16) char lds[32 * 528];
  const int bid = blockIdx.x;
  const int i = bid >> 1, nh = bid & 1;
  const int tid = threadIdx.x;
  const int w = tid >> 6, lane = tid & 63;
  const int alane = lane & 15, q = lane >> 4;

  short8 bw[2][8];
  {
    const char* wb = ws + WF_OFF + (size_t)(nh * 4 + w) * 16384u + (size_t)lane * 16;
#pragma unroll
    for (int nt = 0; nt < 2; ++nt)
#pragma unroll
      for (int ks = 0; ks < 8; ++ks)
        bw[nt][ks] = *(const short8*)(wb + (nt * 8 + ks) * 1024);
  }

  const float* plane = (i < 48) ? src + (size_t)i * 8192 : trg + (size_t)(i - 48) * 8192;
#pragma unroll
  for (int it = 0; it < 4; ++it) {
    int gid = it * 256 + tid;
    int row = gid >> 5, c = gid & 31;
    const float* p = plane + row * 256 + c * 8;
    short8 v;
#pragma unroll
    for (int j = 0; j < 8; ++j) v[j] = f2bf(p[j]);
    *(short8*)(lds + row * 528 + c * 16) = v;
  }
  __syncthreads();

  const f32x4 zf = {0.f, 0.f, 0.f, 0.f};
  f32x4 acc[2][2];
  acc[0][0] = zf; acc[0][1] = zf; acc[1][0] = zf; acc[1][1] = zf;
  const char* ar0 = lds + alane * 528 + q * 16;
  const char* ar1 = lds + (alane + 16) * 528 + q * 16;
#pragma unroll
  for (int ks = 0; ks < 8; ++ks) {
    short8 a0 = *(const short8*)(ar0 + ks * 64);
    short8 a1 = *(const short8*)(ar1 + ks * 64);
#pragma unroll
    for (int nt = 0; nt < 2; ++nt) {
      acc[0][nt] = MFMA16(a0, bw[nt][ks], acc[0][nt]);
      acc[1][nt] = MFMA16(a1, bw[nt][ks], acc[1][nt]);
    }
  }

  const int n0 = nh * 128 + w * 32 + alane;
  float bs[2] = {bvec[n0], bvec[n0 + 16]};
  const int gtid = (nh * 4 + w) * 64 + lane;
  float* dst = (float*)(ws + (i < 48 ? SRCW_OFF : TRGW_OFF)) +
               (size_t)(i < 48 ? i : i - 48) * 8192 + (size_t)gtid * 16;
#pragma unroll
  for (int mt = 0; mt < 2; ++mt)
#pragma unroll
    for (int nt = 0; nt < 2; ++nt) {
      f32x4 v = acc[mt][nt];
      v[0] += bs[nt]; v[1] += bs[nt]; v[2] += bs[nt]; v[3] += bs[nt];
      ((f32x4*)dst)[mt * 2 + nt] = v;
    }
}

// ---------------------------------------------------------------------------
// Kernel 3: persistent systolic grid. 96 blocks x 512 threads = (d, t).
// ---------------------------------------------------------------------------
__global__ __launch_bounds__(512, 2) void grid_main(
    float* __restrict__ out, const float* __restrict__ bvec,
    char* __restrict__ ws) {
  // buf0 = persistent up-image (bf16). Row stride 528B (16B aligned, ~2-way).
  __shared__ __align__(16) char buf0[32 * 528];

  const int bid = blockIdx.x;        // 96 = (d, t)
  const int d = bid / 48;
  const int t = bid % 48;
  const int tid = threadIdx.x;       // 0..511
  const int wv = tid >> 6;           // 0..7
  const int nh = wv >> 2, w = wv & 3;
  const int lane = tid & 63;
  const int alane = lane & 15, q = lane >> 4;
  const int n0 = nh * 128 + w * 32 + alane;

  const float* SRCW = (const float*)(ws + SRCW_OFF);
  const float* TRGW = (const float*)(ws + TRGW_OFF);
  const char* ubp = ws + UF_OFF + (size_t)((d * 2 + nh) * 4 + w) * 32768u +
                    (size_t)lane * 16;

  // zero the up-image: s=0 up operand = 0
  for (int z = tid; z < 32 * 528 / 4; z += 512) ((int*)buf0)[z] = 0;
  __syncthreads();

  const char* up0 = buf0 + alane * 528 + q * 16;
  const char* up1 = buf0 + (alane + 16) * 528 + q * 16;
  const f32x4 zf = {0.f, 0.f, 0.f, 0.f};

  if (d == 0) {
    f32x4 pfy[4];
    {
      const f32x4* py = (const f32x4*)(TRGW + (size_t)t * 8192 + (size_t)tid * 16);
      pfy[0] = py[0]; pfy[1] = py[1]; pfy[2] = py[2]; pfy[3] = py[3];
    }
    for (int s = 0; s < 48; ++s) {
      f32x4 accx[2][2], accy[2][2], accT[2][2];
      {
        const f32x4* px = (const f32x4*)(SRCW + (size_t)s * 8192 + (size_t)tid * 16);
        accx[0][0] = px[0]; accx[0][1] = px[1]; accx[1][0] = px[2]; accx[1][1] = px[3];
      }
      accy[0][0] = pfy[0]; accy[0][1] = pfy[1]; accy[1][0] = pfy[2]; accy[1][1] = pfy[3];
      accT[0][0] = zf; accT[0][1] = zf; accT[1][0] = zf; accT[1][1] = zf;

      // T += up@Ux (block-internal LDS image; off the inter-block path)
#pragma unroll
      for (int ks = 0; ks < 8; ++ks) {
        short8 b0 = *(const short8*)(ubp + (0 * 16 + ks) * 1024);
        short8 b1 = *(const short8*)(ubp + (1 * 16 + ks) * 1024);
        short8 a0 = *(const short8*)(up0 + ks * 64);
        short8 a1 = *(const short8*)(up1 + ks * 64);
        accT[0][0] = MFMA16(a0, b0, accT[0][0]);
        accT[0][1] = MFMA16(a0, b1, accT[0][1]);
        accT[1][0] = MFMA16(a1, b0, accT[1][0]);
        accT[1][1] = MFMA16(a1, b1, accT[1][1]);
      }
      // ring back-pressure: consumers must be done with cell s-8 (slot s&7)
      if (s >= 8) {
        if (t < 47) wait_ge(flagp(ws, FLAG0_OFF, s - 8, t + 1), 8);
        wait_ge(flagp(ws, FLAG1_OFF, s - 8, t), 8);
      }
      // T += left@Uy (direct-to-register coherent loads from staged bf16)
      if (t > 0) {
        wait_ge(flagp(ws, FLAG0_OFF, s, t - 1), 8);
        const char* L = ws + STG0X_OFF + ((size_t)(t - 1) * 8 + (s & 7)) * 16384;
        const char* p0 = L + alane * 512 + q * 16;
        const char* p1 = L + (alane + 16) * 512 + q * 16;
        short8 la0[8], la1[8];
#pragma unroll
        for (int ks = 0; ks < 8; ++ks) {
          la0[ks] = ld_stg16(p0 + ks * 64);
          la1[ks] = ld_stg16(p1 + ks * 64);
        }
#pragma unroll
        for (int ks = 0; ks < 8; ++ks) {
          short8 b0 = *(const short8*)(ubp + (0 * 16 + 8 + ks) * 1024);
          short8 b1 = *(const short8*)(ubp + (1 * 16 + 8 + ks) * 1024);
          accT[0][0] = MFMA16(la0[ks], b0, accT[0][0]);
          accT[0][1] = MFMA16(la0[ks], b1, accT[0][1]);
          accT[1][0] = MFMA16(la1[ks], b0, accT[1][0]);
          accT[1][1] = MFMA16(la1[ks], b1, accT[1][1]);
        }
      }
      // epilogue: hx first (gates the left neighbor), then hy (gates layer 1)
      float hxv[16], hyv[16];
      {
        char* SX = ws + STG0X_OFF + ((size_t)t * 8 + (s & 7)) * 16384;
#pragma unroll
        for (int mt = 0; mt < 2; ++mt)
#pragma unroll
          for (int nt = 0; nt < 2; ++nt)
#pragma unroll
            for (int rr = 0; rr < 4; ++rr) {
              int i = (mt * 2 + nt) * 4 + rr;
              int row = mt * 16 + q * 4 + rr, c = n0 + nt * 16;
              float xv = fast_tanh(accx[mt][nt][rr] + accT[mt][nt][rr]);
              hxv[i] = xv;
              st_llc_u16((unsigned short*)(SX + row * 512 + c * 2),
                         (unsigned short)f2bf(xv));
            }
      }
      asm volatile("s_waitcnt vmcnt(0)" ::: "memory");
      if (lane == 0)
        __hip_atomic_fetch_add(flagp(ws, FLAG0_OFF, s, t), 1,
                               __ATOMIC_RELAXED, __HIP_MEMORY_SCOPE_AGENT);
      {
        char* SY = ws + STG0Y_OFF + ((size_t)t * 8 + (s & 7)) * 16384;
#pragma unroll
        for (int mt = 0; mt < 2; ++mt)
#pragma unroll
          for (int nt = 0; nt < 2; ++nt)
#pragma unroll
            for (int rr = 0; rr < 4; ++rr) {
              int i = (mt * 2 + nt) * 4 + rr;
              int row = mt * 16 + q * 4 + rr, c = n0 + nt * 16;
              float yv = fast_tanh(accy[mt][nt][rr] + accT[mt][nt][rr]);
              hyv[i] = yv;
              st_llc_u16((unsigned short*)(SY + row * 512 + c * 2),
                         (unsigned short)f2bf(yv));
            }
      }
      asm volatile("s_waitcnt vmcnt(0)" ::: "memory");
      if (lane == 0)
        __hip_atomic_fetch_add(flagp(ws, FLAG0_OFF, s, t) + 1, 1,
                               __ATOMIC_RELAXED, __HIP_MEMORY_SCOPE_AGENT);
      // f32 outputs: plain cached stores, nobody consumes them in-kernel.
      {
        float* hxp = out + plane_off(0, s, t, 0);
        float* hyp = out + plane_off(0, s, t, 1);
#pragma unroll
        for (int mt = 0; mt < 2; ++mt)
#pragma unroll
          for (int nt = 0; nt < 2; ++nt)
#pragma unroll
            for (int rr = 0; rr < 4; ++rr) {
              int i = (mt * 2 + nt) * 4 + rr;
              int row = mt * 16 + q * 4 + rr, c = n0 + nt * 16;
              hxp[row * 256 + c] = hxv[i];
              hyp[row * 256 + c] = hyv[i];
            }
      }
      __syncthreads();  // everyone done reading buf0
#pragma unroll
      for (int mt = 0; mt < 2; ++mt)
#pragma unroll
        for (int nt = 0; nt < 2; ++nt)
#pragma unroll
          for (int rr = 0; rr < 4; ++rr) {
            int row = mt * 16 + q * 4 + rr, c = n0 + nt * 16;
            *(short*)(buf0 + row * 528 + c * 2) = f2bf(hxv[(mt * 2 + nt) * 4 + rr]);
          }
      __syncthreads();  // up-image ready for next s
    }
  } else {
    // ---- layer 1 ----
    const char* wbp = ws + WF_OFF + (size_t)((2 + nh) * 4 + w) * 16384u +
                      (size_t)lane * 16;
    const float bsa = bvec[256 + n0], bsb = bvec[256 + n0 + 16];
    const f32x4 bA = {bsa, bsa, bsa, bsa};
    const f32x4 bB = {bsb, bsb, bsb, bsb};
    for (int s = 0; s < 48; ++s) {
      f32x4 accx[2][2], accy[2][2], accT[2][2];
      accx[0][0] = bA; accx[0][1] = bB; accx[1][0] = bA; accx[1][1] = bB;
      accy[0][0] = bA; accy[0][1] = bB; accy[1][0] = bA; accy[1][1] = bB;
      accT[0][0] = zf; accT[0][1] = zf; accT[1][0] = zf; accT[1][1] = zf;

      // T += up1@Ux1
#pragma unroll
      for (int ks = 0; ks < 8; ++ks) {
        short8 b0 = *(const short8*)(ubp + (0 * 16 + ks) * 1024);
        short8 b1 = *(const short8*)(ubp + (1 * 16 + ks) * 1024);
        short8 a0 = *(const short8*)(up0 + ks * 64);
        short8 a1 = *(const short8*)(up1 + ks * 64);
        accT[0][0] = MFMA16(a0, b0, accT[0][0]);
        accT[0][1] = MFMA16(a0, b1, accT[0][1]);
        accT[1][0] = MFMA16(a1, b0, accT[1][0]);
        accT[1][1] = MFMA16(a1, b1, accT[1][1]);
      }
      if (s >= 8 && t < 47) wait_ge(flagp(ws, FLAG1_OFF, s - 8, t + 1), 8);

      // X/Y projections from layer 0's staged bf16 (layer 0 runs ahead)
      wait_ge(flagp(ws, FLAG0_OFF, s, t) + 1, 8);  // flagB0
      {
        const char* X = ws + STG0X_OFF + ((size_t)t * 8 + (s & 7)) * 16384;
        const char* p0 = X + alane * 512 + q * 16;
        const char* p1 = X + (alane + 16) * 512 + q * 16;
        short8 ax0[8], ax1[8];
#pragma unroll
        for (int ks = 0; ks < 8; ++ks) {
          ax0[ks] = ld_stg16(p0 + ks * 64);
          ax1[ks] = ld_stg16(p1 + ks * 64);
        }
#pragma unroll
        for (int ks = 0; ks < 8; ++ks) {
          short8 b0 = *(const short8*)(wbp + ks * 1024);
          short8 b1 = *(const short8*)(wbp + (8 + ks) * 1024);
          accx[0][0] = MFMA16(ax0[ks], b0, accx[0][0]);
          accx[0][1] = MFMA16(ax0[ks], b1, accx[0][1]);
          accx[1][0] = MFMA16(ax1[ks], b0, accx[1][0]);
          accx[1][1] = MFMA16(ax1[ks], b1, accx[1][1]);
        }
      }
      {
        const char* Y = ws + STG0Y_OFF + ((size_t)t * 8 + (s & 7)) * 16384;
        const char* p0 = Y + alane * 512 + q * 16;
        const char* p1 = Y + (alane + 16) * 512 + q * 16;
        short8 ay0[8], ay1[8];
#pragma unroll
        for (int ks = 0; ks < 8; ++ks) {
          ay0[ks] = ld_stg16(p0 + ks * 64);
          ay1[ks] = ld_stg16(p1 + ks * 64);
        }
#pragma unroll
        for (int ks = 0; ks < 8; ++ks) {
          short8 b0 = *(const short8*)(wbp + ks * 1024);
          short8 b1 = *(const short8*)(wbp + (8 + ks) * 1024);
          accy[0][0] = MFMA16(ay0[ks], b0, accy[0][0]);
          accy[0][1] = MFMA16(ay0[ks], b1, accy[0][1]);
          accy[1][0] = MFMA16(ay1[ks], b0, accy[1][0]);
          accy[1][1] = MFMA16(ay1[ks], b1, accy[1][1]);
        }
      }
      // T += left1@Uy1
      if (t > 0) {
        wait_ge(flagp(ws, FLAG1_OFF, s, t - 1), 8);
        const char* L = ws + STG1X_OFF + ((size_t)(t - 1) * 8 + (s & 7)) * 16384;
        const char* p0 = L + alane * 512 + q * 16;
        const char* p1 = L + (alane + 16) * 512 + q * 16;
        short8 la0[8], la1[8];
#pragma unroll
        for (int ks = 0; ks < 8; ++ks) {
          la0[ks] = ld_stg16(p0 + ks * 64);
          la1[ks] = ld_stg16(p1 + ks * 64);
        }
#pragma unroll
        for (int ks = 0; ks < 8; ++ks) {
          short8 b0 = *(const short8*)(ubp + (0 * 16 + 8 + ks) * 1024);
          short8 b1 = *(const short8*)(ubp + (1 * 16 + 8 + ks) * 1024);
          accT[0][0] = MFMA16(la0[ks], b0, accT[0][0]);
          accT[0][1] = MFMA16(la0[ks], b1, accT[0][1]);
          accT[1][0] = MFMA16(la1[ks], b0, accT[1][0]);
          accT[1][1] = MFMA16(la1[ks], b1, accT[1][1]);
        }
      }
      // epilogue
      float hxv[16], hyv[16];
      {
        char* SX = ws + STG1X_OFF + ((size_t)t * 8 + (s & 7)) * 16384;
#pragma unroll
        for (int mt = 0; mt < 2; ++mt)
#pragma unroll
          for (int nt = 0; nt < 2; ++nt)
#pragma unroll
            for (int rr = 0; rr < 4; ++rr) {
              int i = (mt * 2 + nt) * 4 + rr;
              int row = mt * 16 + q * 4 + rr, c = n0 + nt * 16;
              float xv = fast_tanh(accx[mt][nt][rr] + accT[mt][nt][rr]);
              hxv[i] = xv;
              if (t < 47)
                st_llc_u16((unsigned short*)(SX + row * 512 + c * 2),
                           (unsigned short)f2bf(xv));
            }
      }
      asm volatile("s_waitcnt vmcnt(0)" ::: "memory");
      if (lane == 0)
        __hip_atomic_fetch_add(flagp(ws, FLAG1_OFF, s, t), 1,
                               __ATOMIC_RELAXED, __HIP_MEMORY_SCOPE_AGENT);
#pragma unroll
      for (int mt = 0; mt < 2; ++mt)
#pragma unroll
        for (int nt = 0; nt < 2; ++nt)
#pragma unroll
          for (int rr = 0; rr < 4; ++rr)
            hyv[(mt * 2 + nt) * 4 + rr] =
                fast_tanh(accy[mt][nt][rr] + accT[mt][nt][rr]);
      {
        float* hxp = out + plane_off(1, s, t, 0);
        float* hyp = out + plane_off(1, s, t, 1);
#pragma unroll
        for (int mt = 0; mt < 2; ++mt)
#pragma unroll
          for (int nt = 0; nt < 2; ++nt)
#pragma unroll
            for (int rr = 0; rr < 4; ++rr) {
              int i = (mt * 2 + nt) * 4 + rr;
              int row = mt * 16 + q * 4 + rr, c = n0 + nt * 16;
              hxp[row * 256 + c] = hxv[i];
              hyp[row * 256 + c] = hyv[i];
            }
      }
      __syncthreads();  // everyone done reading buf0
#pragma unroll
      for (int mt = 0; mt < 2; ++mt)
#pragma unroll
        for (int nt = 0; nt < 2; ++nt)
#pragma unroll
          for (int rr = 0; rr < 4; ++rr) {
            int row = mt * 16 + q * 4 + rr, c = n0 + nt * 16;
            *(short*)(buf0 + row * 528 + c * 2) = f2bf(hxv[(mt * 2 + nt) * 4 + rr]);
          }
      __syncthreads();  // up-image ready for next s
    }
  }
}

extern "C" void kernel_launch(void* const* d_in, const int* in_sizes, int n_in,
                              void* d_out, int out_size, void* d_ws, size_t ws_size,
                              hipStream_t stream) {
  const float* src = (const float*)d_in[0];
  const float* trg = (const float*)d_in[1];
  const float* W   = (const float*)d_in[2];
  const float* U   = (const float*)d_in[3];
  const float* bv  = (const float*)d_in[4];
  float* out = (float*)d_out;
  char* ws = (char*)d_ws;

  hipMemsetAsync(ws + FLAG0_OFF, 0, 2u * 48 * 48 * 128, stream);
  preswizzle<<<192, 256, 0, stream>>>(U, W, ws);
  precompute_xw<<<192, 256, 0, stream>>>(src, trg, bv, ws);
  grid_main<<<96, 512, 0, stream>>>(out, bv, ws);
}

// Round 3
// 816.776 us; speedup vs baseline: 4.3756x; 4.3756x over previous
//
#include <hip/hip_runtime.h>
#include <hip/hip_bf16.h>

// Grid LSTM (tanh grid-RNN), D=2, S=T=48, B=32, H=256. f32 in/out; bf16 MFMA
// internally. Persistent systolic columns, one block per (d, t) walking s.
// v4 = v2 handoff (bypass f32 stores -> LLC, vmcnt drain, relaxed flag add;
// consumers poll relaxed + plain cached loads, each address read once per
// block per launch) with per-cell serial time cut down:
//  - __launch_bounds__(512,1): 256-VGPR budget so the U B-fragment set
//    bu[2][16] (128 VGPRs) is register-resident (v2's bounds(512,2) forced
//    ~256KB/cell of B-fragment re-streaming from L2 on the MFMA path).
//  - shared-T: T = up@Ux + left@Uy computed ONCE (64 MFMAs), added to both
//    accx and accy in the epilogue (layer 0 was 128 MFMAs in v2).
//  - split flags: flagA after hx-plane drain (gates right neighbor; half the
//    drain), flagB after hy-plane drain (gates layer 1 only).
//  - overlap: left-plane loads issued right after the wait; up-MFMA (LDS
//    buf0 only) runs under their latency; then cvt -> LDS -> barrier -> MFMA.

typedef short short8 __attribute__((ext_vector_type(8)));
typedef float f32x4 __attribute__((ext_vector_type(4)));

static constexpr size_t UF_OFF    = 0;                           // 512 KiB U frags (bf16)
static constexpr size_t WF_OFF    = 512u * 1024;                 // 256 KiB W frags (bf16)
static constexpr size_t SRCW_OFF  = 768u * 1024;                 // 1.5 MiB f32 (acc layout)
static constexpr size_t TRGW_OFF  = SRCW_OFF + 48u * 32 * 256 * 4;
static constexpr size_t FLAG0_OFF = TRGW_OFF + 48u * 32 * 256 * 4;  // 48*48 lines x 128B
static constexpr size_t FLAG1_OFF = FLAG0_OFF + 48u * 48 * 128;

#define MFMA16(a, b, c) __builtin_amdgcn_mfma_f32_16x16x32_bf16(a, b, c, 0, 0, 0)

__device__ __forceinline__ short f2bf(float f) {
  __hip_bfloat16 h = __float2bfloat16(f);
  return __builtin_bit_cast(short, h);
}

__device__ __forceinline__ size_t plane_off(int d, int s, int t, int c) {
  return (size_t)(((d * 48 + s) * 48 + t) * 2 + c) * 8192u;  // f32 elements
}

__device__ __forceinline__ int* flagp(char* ws, size_t off, int s, int t) {
  return (int*)(ws + off) + (size_t)(s * 48 + t) * 32;  // one 128B line per cell
}

__device__ __forceinline__ void wait_ge(int* p, int v) {
  while (__hip_atomic_load(p, __ATOMIC_RELAXED, __HIP_MEMORY_SCOPE_AGENT) < v)
    __builtin_amdgcn_s_sleep(1);
  asm volatile("" ::: "memory");  // keep subsequent loads below the spin
}

// write-through to LLC (sc0 sc1): visible agent-wide once vmcnt retires.
__device__ __forceinline__ void st_llc(float* p, float v) {
  __hip_atomic_store(p, v, __ATOMIC_RELAXED, __HIP_MEMORY_SCOPE_AGENT);
}

__device__ __forceinline__ float fast_tanh(float x) {
  float e = exp2f(x * 2.88539008f);
  return 1.f - __fdividef(2.f, e + 1.f);
}

// ---------------------------------------------------------------------------
// Kernel 1: U (2,512,256) f32 and W (2,256,256) f32 -> bf16 MFMA B-fragments.
// ---------------------------------------------------------------------------
__global__ void preswizzle(const float* __restrict__ U,
                           const float* __restrict__ W,
                           char* __restrict__ ws) {
  int gid = blockIdx.x * 256 + threadIdx.x;
  if (gid < 32768) {  // U
    int r = gid >> 11;
    int d = r >> 3, nh = (r >> 2) & 1, w = r & 3;
    int c = gid & 2047;
    int f = c >> 6, lane = c & 63;
    int nt = f >> 4, ks = f & 15;
    int kbase = ks * 32 + (lane >> 4) * 8;
    int n = nh * 128 + w * 32 + nt * 16 + (lane & 15);
    const float* sp = U + (size_t)d * 512 * 256 + n;
    short8 v;
#pragma unroll
    for (int j = 0; j < 8; ++j) v[j] = f2bf(sp[(size_t)(kbase + j) * 256]);
    *(short8*)(ws + UF_OFF + (size_t)gid * 16) = v;
  } else {            // W
    int idx = gid - 32768;
    int r = idx >> 10;
    int d = r >> 3, nh = (r >> 2) & 1, w = r & 3;
    int c = idx & 1023;
    int f = c >> 6, lane = c & 63;
    int nt = f >> 3, ks = f & 7;
    int kbase = ks * 32 + (lane >> 4) * 8;
    int n = nh * 128 + w * 32 + nt * 16 + (lane & 15);
    const float* sp = W + (size_t)d * 256 * 256 + n;
    short8 v;
#pragma unroll
    for (int j = 0; j < 8; ++j) v[j] = f2bf(sp[(size_t)(kbase + j) * 256]);
    *(short8*)(ws + WF_OFF + (size_t)idx * 16) = v;
  }
}

// ---------------------------------------------------------------------------
// Kernel 2: SRCW[s] = src[s]@W0 + b0 ; TRGW[t] = trg[t]@W0 + b0  (f32),
// stored in grid_main's per-thread accumulator layout: [i][gtid][16].
// ---------------------------------------------------------------------------
__global__ __launch_bounds__(256, 1) void precompute_xw(
    const float* __restrict__ src, const float* __restrict__ trg,
    const float* __restrict__ bvec, char* __restrict__ ws) {
  __shared__ __align__(16) char lds[32 * 528];
  const int bid = blockIdx.x;
  const int i = bid >> 1, nh = bid & 1;
  const int tid = threadIdx.x;
  const int w = tid >> 6, lane = tid & 63;
  const int alane = lane & 15, q = lane >> 4;

  short8 bw[2][8];
  {
    const char* wb = ws + WF_OFF + (size_t)(nh * 4 + w) * 16384u + (size_t)lane * 16;
#pragma unroll
    for (int nt = 0; nt < 2; ++nt)
#pragma unroll
      for (int ks = 0; ks < 8; ++ks)
        bw[nt][ks] = *(const short8*)(wb + (nt * 8 + ks) * 1024);
  }

  const float* plane = (i < 48) ? src + (size_t)i * 8192 : trg + (size_t)(i - 48) * 8192;
#pragma unroll
  for (int it = 0; it < 4; ++it) {
    int gid = it * 256 + tid;
    int row = gid >> 5, c = gid & 31;
    const float* p = plane + row * 256 + c * 8;
    short8 v;
#pragma unroll
    for (int j = 0; j < 8; ++j) v[j] = f2bf(p[j]);
    *(short8*)(lds + row * 528 + c * 16) = v;
  }
  __syncthreads();

  const f32x4 zf = {0.f, 0.f, 0.f, 0.f};
  f32x4 acc[2][2];
  acc[0][0] = zf; acc[0][1] = zf; acc[1][0] = zf; acc[1][1] = zf;
  const char* ar0 = lds + alane * 528 + q * 16;
  const char* ar1 = lds + (alane + 16) * 528 + q * 16;
#pragma unroll
  for (int ks = 0; ks < 8; ++ks) {
    short8 a0 = *(const short8*)(ar0 + ks * 64);
    short8 a1 = *(const short8*)(ar1 + ks * 64);
#pragma unroll
    for (int nt = 0; nt < 2; ++nt) {
      acc[0][nt] = MFMA16(a0, bw[nt][ks], acc[0][nt]);
      acc[1][nt] = MFMA16(a1, bw[nt][ks], acc[1][nt]);
    }
  }

  const int n0 = nh * 128 + w * 32 + alane;
  float bs[2] = {bvec[n0], bvec[n0 + 16]};
  const int gtid = (nh * 4 + w) * 64 + lane;
  float* dst = (float*)(ws + (i < 48 ? SRCW_OFF : TRGW_OFF)) +
               (size_t)(i < 48 ? i : i - 48) * 8192 + (size_t)gtid * 16;
#pragma unroll
  for (int mt = 0; mt < 2; ++mt)
#pragma unroll
    for (int nt = 0; nt < 2; ++nt) {
      f32x4 v = acc[mt][nt];
      v[0] += bs[nt]; v[1] += bs[nt]; v[2] += bs[nt]; v[3] += bs[nt];
      ((f32x4*)dst)[mt * 2 + nt] = v;
    }
}

// ---------------------------------------------------------------------------
// Kernel 3: persistent systolic grid. 96 blocks x 512 threads = (d, t).
// ---------------------------------------------------------------------------
__global__ __launch_bounds__(512, 1) void grid_main(
    float* __restrict__ out, const float* __restrict__ bvec,
    char* __restrict__ ws) {
  // buf0 = persistent up-image; buf1 = left/x; buf2 = y; buf3 = left1.
  __shared__ __align__(16) char lds[4 * 32 * 528];
  char* const buf0 = lds;
  char* const buf1 = lds + 32 * 528;
  char* const buf2 = lds + 2 * 32 * 528;
  char* const buf3 = lds + 3 * 32 * 528;

  const int bid = blockIdx.x;        // 96 = (d, t)
  const int d = bid / 48;
  const int t = bid % 48;
  const int tid = threadIdx.x;       // 0..511
  const int wv = tid >> 6;           // 0..7
  const int nh = wv >> 2, w = wv & 3;
  const int lane = tid & 63;
  const int alane = lane & 15, q = lane >> 4;
  const int n0 = nh * 128 + w * 32 + alane;

  const float* SRCW = (const float*)(ws + SRCW_OFF);
  const float* TRGW = (const float*)(ws + TRGW_OFF);

  // U B-frags in registers (256-VGPR budget at occupancy 1):
  // bu[nt][ks]; ks 0..7 = Ux (up), 8..15 = Uy (left).
  short8 bu[2][16];
  {
    const char* ub = ws + UF_OFF + (size_t)((d * 2 + nh) * 4 + w) * 32768u +
                     (size_t)lane * 16;
#pragma unroll
    for (int nt = 0; nt < 2; ++nt)
#pragma unroll
      for (int ks = 0; ks < 16; ++ks)
        bu[nt][ks] = *(const short8*)(ub + (nt * 16 + ks) * 1024);
  }

  // zero the up-image: s=0 up operand = 0
  for (int z = tid; z < 32 * 528 / 4; z += 512) ((int*)buf0)[z] = 0;
  __syncthreads();

  const char* up0 = buf0 + alane * 528 + q * 16;
  const char* up1 = buf0 + (alane + 16) * 528 + q * 16;
  const char* l0  = buf1 + alane * 528 + q * 16;
  const char* l1  = buf1 + (alane + 16) * 528 + q * 16;
  const char* y0  = buf2 + alane * 528 + q * 16;
  const char* y1  = buf2 + (alane + 16) * 528 + q * 16;
  const char* m0  = buf3 + alane * 528 + q * 16;
  const char* m1  = buf3 + (alane + 16) * 528 + q * 16;
  const f32x4 zf = {0.f, 0.f, 0.f, 0.f};

  if (d == 0) {
    // TRGW[t] C-init (acc layout), constant over s.
    f32x4 pfy[4];
    {
      const f32x4* py = (const f32x4*)(TRGW + (size_t)t * 8192 + (size_t)tid * 16);
      pfy[0] = py[0]; pfy[1] = py[1]; pfy[2] = py[2]; pfy[3] = py[3];
    }
    for (int s = 0; s < 48; ++s) {
      f32x4 accx[2][2], accy[2][2], accT[2][2];
      {
        const f32x4* px = (const f32x4*)(SRCW + (size_t)s * 8192 + (size_t)tid * 16);
        accx[0][0] = px[0]; accx[0][1] = px[1]; accx[1][0] = px[2]; accx[1][1] = px[3];
      }
      accy[0][0] = pfy[0]; accy[0][1] = pfy[1]; accy[1][0] = pfy[2]; accy[1][1] = pfy[3];
      accT[0][0] = zf; accT[0][1] = zf; accT[1][0] = zf; accT[1][1] = zf;

      // Wait for left, then ISSUE its loads; up-MFMA runs under the latency.
      f32x4 lva[2], lvb[2];
      if (t > 0) {
        wait_ge(flagp(ws, FLAG0_OFF, s, t - 1), 8);  // flagA: hx drained
        const float* pl = out + plane_off(0, s, t - 1, 0);
#pragma unroll
        for (int it = 0; it < 2; ++it) {
          int gid = it * 512 + tid;
          int row = gid >> 5, c = gid & 31;
          const float* p = pl + row * 256 + c * 8;
          lva[it] = *(const f32x4*)p;
          lvb[it] = *(const f32x4*)(p + 4);
        }
      }
      // T += up@Ux (LDS buf0 only; independent of the left loads)
#pragma unroll
      for (int ks = 0; ks < 8; ++ks) {
        short8 a0 = *(const short8*)(up0 + ks * 64);
        short8 a1 = *(const short8*)(up1 + ks * 64);
        accT[0][0] = MFMA16(a0, bu[0][ks], accT[0][0]);
        accT[0][1] = MFMA16(a0, bu[1][ks], accT[0][1]);
        accT[1][0] = MFMA16(a1, bu[0][ks], accT[1][0]);
        accT[1][1] = MFMA16(a1, bu[1][ks], accT[1][1]);
      }
      if (t > 0) {
#pragma unroll
        for (int it = 0; it < 2; ++it) {
          int gid = it * 512 + tid;
          int row = gid >> 5, c = gid & 31;
          short8 v;
#pragma unroll
          for (int j = 0; j < 4; ++j) {
            v[j] = f2bf(lva[it][j]);
            v[4 + j] = f2bf(lvb[it][j]);
          }
          *(short8*)(buf1 + row * 528 + c * 16) = v;
        }
      }
      __syncthreads();  // B1: left image staged; also: all waves did up-MFMA
      if (t > 0) {
#pragma unroll
        for (int ks = 0; ks < 8; ++ks) {
          short8 a0 = *(const short8*)(l0 + ks * 64);
          short8 a1 = *(const short8*)(l1 + ks * 64);
          accT[0][0] = MFMA16(a0, bu[0][8 + ks], accT[0][0]);
          accT[0][1] = MFMA16(a0, bu[1][8 + ks], accT[0][1]);
          accT[1][0] = MFMA16(a1, bu[0][8 + ks], accT[1][0]);
          accT[1][1] = MFMA16(a1, bu[1][8 + ks], accT[1][1]);
        }
      }
      // Epilogue: hx first (gates right neighbor), flagA, then hy, flagB.
      float hxv[16];
      {
        float* hxp = out + plane_off(0, s, t, 0);
#pragma unroll
        for (int mt = 0; mt < 2; ++mt)
#pragma unroll
          for (int nt = 0; nt < 2; ++nt)
#pragma unroll
            for (int rr = 0; rr < 4; ++rr) {
              int i = (mt * 2 + nt) * 4 + rr;
              int row = mt * 16 + q * 4 + rr, c = n0 + nt * 16;
              float xv = fast_tanh(accx[mt][nt][rr] + accT[mt][nt][rr]);
              hxv[i] = xv;
              st_llc(&hxp[row * 256 + c], xv);
            }
      }
      asm volatile("s_waitcnt vmcnt(0)" ::: "memory");
      if (lane == 0)
        __hip_atomic_fetch_add(flagp(ws, FLAG0_OFF, s, t), 1,
                               __ATOMIC_RELAXED, __HIP_MEMORY_SCOPE_AGENT);
      {
        float* hyp = out + plane_off(0, s, t, 1);
#pragma unroll
        for (int mt = 0; mt < 2; ++mt)
#pragma unroll
          for (int nt = 0; nt < 2; ++nt)
#pragma unroll
            for (int rr = 0; rr < 4; ++rr) {
              int row = mt * 16 + q * 4 + rr, c = n0 + nt * 16;
              st_llc(&hyp[row * 256 + c],
                     fast_tanh(accy[mt][nt][rr] + accT[mt][nt][rr]));
            }
      }
      asm volatile("s_waitcnt vmcnt(0)" ::: "memory");
      if (lane == 0)
        __hip_atomic_fetch_add(flagp(ws, FLAG0_OFF, s, t) + 1, 1,
                               __ATOMIC_RELAXED, __HIP_MEMORY_SCOPE_AGENT);
      // Refresh the persistent up-image (others are past B1; they only touch
      // buf1 afterwards, so writing buf0 here is race-free).
#pragma unroll
      for (int mt = 0; mt < 2; ++mt)
#pragma unroll
        for (int nt = 0; nt < 2; ++nt)
#pragma unroll
          for (int rr = 0; rr < 4; ++rr) {
            int row = mt * 16 + q * 4 + rr, c = n0 + nt * 16;
            *(short*)(buf0 + row * 528 + c * 2) = f2bf(hxv[(mt * 2 + nt) * 4 + rr]);
          }
      __syncthreads();  // B2: up-image ready for next s
    }
  } else {
    // ---- layer 1 ----
    const char* wbp = ws + WF_OFF + (size_t)((2 + nh) * 4 + w) * 16384u +
                      (size_t)lane * 16;
    const float bsa = bvec[256 + n0], bsb = bvec[256 + n0 + 16];
    const f32x4 bA = {bsa, bsa, bsa, bsa};
    const f32x4 bB = {bsb, bsb, bsb, bsb};
    for (int s = 0; s < 48; ++s) {
      f32x4 accx[2][2], accy[2][2], accT[2][2];
      accx[0][0] = bA; accx[0][1] = bB; accx[1][0] = bA; accx[1][1] = bB;
      accy[0][0] = bA; accy[0][1] = bB; accy[1][0] = bA; accy[1][1] = bB;
      accT[0][0] = zf; accT[0][1] = zf; accT[1][0] = zf; accT[1][1] = zf;

      // Wait for layer-0 x/y, issue their loads; up1-MFMA under the latency.
      wait_ge(flagp(ws, FLAG0_OFF, s, t) + 1, 8);  // flagB0: hx0+hy0 drained
      f32x4 xva[4], xvb[4];
      {
        const float* px = out + plane_off(0, s, t, 0);
        const float* py = out + plane_off(0, s, t, 1);
#pragma unroll
        for (int it = 0; it < 4; ++it) {
          int gid = it * 512 + tid;
          int pidx = gid >> 10, row = (gid >> 5) & 31, c = gid & 31;
          const float* pp = (pidx ? py : px) + row * 256 + c * 8;
          xva[it] = *(const f32x4*)pp;
          xvb[it] = *(const f32x4*)(pp + 4);
        }
      }
      // T += up1@Ux1
#pragma unroll
      for (int ks = 0; ks < 8; ++ks) {
        short8 a0 = *(const short8*)(up0 + ks * 64);
        short8 a1 = *(const short8*)(up1 + ks * 64);
        accT[0][0] = MFMA16(a0, bu[0][ks], accT[0][0]);
        accT[0][1] = MFMA16(a0, bu[1][ks], accT[0][1]);
        accT[1][0] = MFMA16(a1, bu[0][ks], accT[1][0]);
        accT[1][1] = MFMA16(a1, bu[1][ks], accT[1][1]);
      }
      {
#pragma unroll
        for (int it = 0; it < 4; ++it) {
          int gid = it * 512 + tid;
          int pidx = gid >> 10, row = (gid >> 5) & 31, c = gid & 31;
          char* db = pidx ? buf2 : buf1;
          short8 v;
#pragma unroll
          for (int j = 0; j < 4; ++j) {
            v[j] = f2bf(xva[it][j]);
            v[4 + j] = f2bf(xvb[it][j]);
          }
          *(short8*)(db + row * 528 + c * 16) = v;
        }
      }
      __syncthreads();  // B1: x/y staged
      // accx += hx0@W1, accy += hy0@W1 (bw streamed from L1/L2-hot ws)
#pragma unroll
      for (int ks = 0; ks < 8; ++ks) {
        short8 b0 = *(const short8*)(wbp + ks * 1024);
        short8 b1 = *(const short8*)(wbp + (8 + ks) * 1024);
        short8 ax0 = *(const short8*)(l0 + ks * 64);
        short8 ax1 = *(const short8*)(l1 + ks * 64);
        short8 ay0 = *(const short8*)(y0 + ks * 64);
        short8 ay1 = *(const short8*)(y1 + ks * 64);
        accx[0][0] = MFMA16(ax0, b0, accx[0][0]);
        accx[0][1] = MFMA16(ax0, b1, accx[0][1]);
        accx[1][0] = MFMA16(ax1, b0, accx[1][0]);
        accx[1][1] = MFMA16(ax1, b1, accx[1][1]);
        accy[0][0] = MFMA16(ay0, b0, accy[0][0]);
        accy[0][1] = MFMA16(ay0, b1, accy[0][1]);
        accy[1][0] = MFMA16(ay1, b0, accy[1][0]);
        accy[1][1] = MFMA16(ay1, b1, accy[1][1]);
      }
      // left1 into buf3 (own buffer -> only one barrier needed)
      if (t > 0) {
        wait_ge(flagp(ws, FLAG1_OFF, s, t - 1), 8);
        const float* pl = out + plane_off(1, s, t - 1, 0);
        f32x4 lva[2], lvb[2];
#pragma unroll
        for (int it = 0; it < 2; ++it) {
          int gid = it * 512 + tid;
          int row = gid >> 5, c = gid & 31;
          const float* p = pl + row * 256 + c * 8;
          lva[it] = *(const f32x4*)p;
          lvb[it] = *(const f32x4*)(p + 4);
        }
#pragma unroll
        for (int it = 0; it < 2; ++it) {
          int gid = it * 512 + tid;
          int row = gid >> 5, c = gid & 31;
          short8 v;
#pragma unroll
          for (int j = 0; j < 4; ++j) {
            v[j] = f2bf(lva[it][j]);
            v[4 + j] = f2bf(lvb[it][j]);
          }
          *(short8*)(buf3 + row * 528 + c * 16) = v;
        }
      }
      __syncthreads();  // B2: left1 staged
      if (t > 0) {
#pragma unroll
        for (int ks = 0; ks < 8; ++ks) {
          short8 a0 = *(const short8*)(m0 + ks * 64);
          short8 a1 = *(const short8*)(m1 + ks * 64);
          accT[0][0] = MFMA16(a0, bu[0][8 + ks], accT[0][0]);
          accT[0][1] = MFMA16(a0, bu[1][8 + ks], accT[0][1]);
          accT[1][0] = MFMA16(a1, bu[0][8 + ks], accT[1][0]);
          accT[1][1] = MFMA16(a1, bu[1][8 + ks], accT[1][1]);
        }
      }
      // Epilogue: hx1 (consumed by right neighbor) -> bypass + flag; hy1 is
      // final-output-only -> plain cached stores, after the flag.
      float hxv[16];
      {
        float* hxp = out + plane_off(1, s, t, 0);
#pragma unroll
        for (int mt = 0; mt < 2; ++mt)
#pragma unroll
          for (int nt = 0; nt < 2; ++nt)
#pragma unroll
            for (int rr = 0; rr < 4; ++rr) {
              int i = (mt * 2 + nt) * 4 + rr;
              int row = mt * 16 + q * 4 + rr, c = n0 + nt * 16;
              float xv = fast_tanh(accx[mt][nt][rr] + accT[mt][nt][rr]);
              hxv[i] = xv;
              st_llc(&hxp[row * 256 + c], xv);
            }
      }
      asm volatile("s_waitcnt vmcnt(0)" ::: "memory");
      if (lane == 0)
        __hip_atomic_fetch_add(flagp(ws, FLAG1_OFF, s, t), 1,
                               __ATOMIC_RELAXED, __HIP_MEMORY_SCOPE_AGENT);
      {
        float* hyp = out + plane_off(1, s, t, 1);
#pragma unroll
        for (int mt = 0; mt < 2; ++mt)
#pragma unroll
          for (int nt = 0; nt < 2; ++nt)
#pragma unroll
            for (int rr = 0; rr < 4; ++rr) {
              int row = mt * 16 + q * 4 + rr, c = n0 + nt * 16;
              hyp[row * 256 + c] =
                  fast_tanh(accy[mt][nt][rr] + accT[mt][nt][rr]);
            }
      }
      // Refresh up-image (others past B2; they only touch out/buf3 after).
#pragma unroll
      for (int mt = 0; mt < 2; ++mt)
#pragma unroll
        for (int nt = 0; nt < 2; ++nt)
#pragma unroll
          for (int rr = 0; rr < 4; ++rr) {
            int row = mt * 16 + q * 4 + rr, c = n0 + nt * 16;
            *(short*)(buf0 + row * 528 + c * 2) = f2bf(hxv[(mt * 2 + nt) * 4 + rr]);
          }
      __syncthreads();  // B3: up-image ready for next s
    }
  }
}

extern "C" void kernel_launch(void* const* d_in, const int* in_sizes, int n_in,
                              void* d_out, int out_size, void* d_ws, size_t ws_size,
                              hipStream_t stream) {
  const float* src = (const float*)d_in[0];
  const float* trg = (const float*)d_in[1];
  const float* W   = (const float*)d_in[2];
  const float* U   = (const float*)d_in[3];
  const float* bv  = (const float*)d_in[4];
  float* out = (float*)d_out;
  char* ws = (char*)d_ws;

  hipMemsetAsync(ws + FLAG0_OFF, 0, 2u * 48 * 48 * 128, stream);
  preswizzle<<<192, 256, 0, stream>>>(U, W, ws);
  precompute_xw<<<192, 256, 0, stream>>>(src, trg, bv, ws);
  grid_main<<<96, 512, 0, stream>>>(out, bv, ws);
}